// Round 8
// baseline (976.084 us; speedup 1.0000x reference)
//
#include <hip/hip_runtime.h>

// SingleHeadAttention: B=4, T=4096, C=1024, causal. fp32 in/out, bf16 MFMA internally.
// Pipeline: [cvt x,w_qkv -> bf16] -> [gemm_bt qkv->Q,K4,Vb] -> [transpose_v4]
//           -> [flash] -> [gemm_bt out]
// ws (u16 elems): Qb[16M] | K4[16M] | Vb[16M] | V4[16M] | ao[16M] = 167.8 MB
//   xb (bf16 x) SHARES the ao slot (dead before flash writes ao);
//   wqb (bf16 w_qkv) lives at the FRONT of the V4 slot (dead before
//   transpose_v4 writes V4). Stream order guarantees both.
//
// v8 = v7 + bf16 pre-conversion of the qkv GEMM inputs: the fp32 staging path
// loaded 64 B/thread/K-step + 32 f2bf VALU ops in the hot loop (Common-mistake
// #2, 2-2.5x). Now both GEMM operands stage as 16 B uint4 bf16.
// v7 (verified): fragment-major K4/V4 -> coalesced 1KB MFMA operand loads,
// flash 524->289 us. Causal pairing + asc/desc sweeps keep K/V L3-resident.

typedef unsigned short u16;
typedef float f32x4 __attribute__((ext_vector_type(4)));
typedef __bf16 bf16x8 __attribute__((ext_vector_type(8)));

__device__ __forceinline__ u16 f2bf(float f) {
  __bf16 h = (__bf16)f;
  return __builtin_bit_cast(u16, h);
}

// LDS-only barrier: drain own LDS ops, sync; global loads stay in flight.
__device__ __forceinline__ void lds_barrier() {
  asm volatile("s_waitcnt lgkmcnt(0)" ::: "memory");
  __builtin_amdgcn_s_barrier();
}

// ---------------------------------------------------------------------------
// fp32 -> bf16, 8 elems/thread (2x float4 in, 1x uint4 out).
// ---------------------------------------------------------------------------
__global__ __launch_bounds__(256) void cvt_bf16(const float* __restrict__ src,
                                                u16* __restrict__ dst, int n8) {
  const int i = blockIdx.x * 256 + threadIdx.x;
  if (i < n8) {
    float4 a = ((const float4*)src)[2 * i];
    float4 b = ((const float4*)src)[2 * i + 1];
    u16 t[8] = {f2bf(a.x), f2bf(a.y), f2bf(a.z), f2bf(a.w),
                f2bf(b.x), f2bf(b.y), f2bf(b.z), f2bf(b.w)};
    ((uint4*)dst)[i] = *(const uint4*)t;
  }
}

// ---------------------------------------------------------------------------
// C[M][N] = A[M][K] @ B[N][K]^T  (bf16 MFMA, fp32 accumulate).
// MODE 0: plain row-major C. MODE 1 (QKV split): C is ws base; cols 0..1023
// -> Qb row-major, 1024..2047 -> K4 fragment-major, 2048..3071 -> Vb row-major.
// 128x128 tile, BK=32, 4 waves 2x2, each wave 64x64 via 4x4 MFMA 16x16x32.
// ---------------------------------------------------------------------------
template <typename TA, typename TB, typename TC, int MODE>
__global__ __launch_bounds__(256) void gemm_bt(const TA* __restrict__ A,
                                               const TB* __restrict__ B,
                                               TC* __restrict__ C,
                                               int M, int N, int K) {
  constexpr int LDT = 40;
  __shared__ u16 As[128 * LDT];
  __shared__ u16 Bs[128 * LDT];
  const int tid = threadIdx.x;
  const int lane = tid & 63, wv = tid >> 6;
  const int l15 = lane & 15, l4 = lane >> 4;
  const int bm = blockIdx.y * 128, bn = blockIdx.x * 128;
  const int wm = (wv >> 1) * 64, wn = (wv & 1) * 64;
  const int srow = tid >> 1, scol = (tid & 1) * 16;  // each thread stages 16 elems of one row
  const TA* ag = A + (size_t)(bm + srow) * K + scol;
  const TB* bg = B + (size_t)(bn + srow) * K + scol;

  float4 paf[4], pbf[4];
  uint4 pau[2], pbu[2];

  auto loadA = [&](int off) {
    if constexpr (sizeof(TA) == 4) {
#pragma unroll
      for (int i = 0; i < 4; ++i) paf[i] = *(const float4*)((const float*)ag + off + 4 * i);
    } else {
      pau[0] = *(const uint4*)((const u16*)ag + off);
      pau[1] = *(const uint4*)((const u16*)ag + off + 8);
    }
  };
  auto loadB = [&](int off) {
    if constexpr (sizeof(TB) == 4) {
#pragma unroll
      for (int i = 0; i < 4; ++i) pbf[i] = *(const float4*)((const float*)bg + off + 4 * i);
    } else {
      pbu[0] = *(const uint4*)((const u16*)bg + off);
      pbu[1] = *(const uint4*)((const u16*)bg + off + 8);
    }
  };
  auto storeA = [&](u16* dst) {
    if constexpr (sizeof(TA) == 4) {
      u16 t[16];
#pragma unroll
      for (int i = 0; i < 4; ++i) {
        t[i * 4 + 0] = f2bf(paf[i].x); t[i * 4 + 1] = f2bf(paf[i].y);
        t[i * 4 + 2] = f2bf(paf[i].z); t[i * 4 + 3] = f2bf(paf[i].w);
      }
      *(uint4*)dst = *(const uint4*)&t[0];
      *(uint4*)(dst + 8) = *(const uint4*)&t[8];
    } else {
      *(uint4*)dst = pau[0];
      *(uint4*)(dst + 8) = pau[1];
    }
  };
  auto storeB = [&](u16* dst) {
    if constexpr (sizeof(TB) == 4) {
      u16 t[16];
#pragma unroll
      for (int i = 0; i < 4; ++i) {
        t[i * 4 + 0] = f2bf(pbf[i].x); t[i * 4 + 1] = f2bf(pbf[i].y);
        t[i * 4 + 2] = f2bf(pbf[i].z); t[i * 4 + 3] = f2bf(pbf[i].w);
      }
      *(uint4*)dst = *(const uint4*)&t[0];
      *(uint4*)(dst + 8) = *(const uint4*)&t[8];
    } else {
      *(uint4*)dst = pbu[0];
      *(uint4*)(dst + 8) = pbu[1];
    }
  };

  f32x4 acc[4][4] = {};
  loadA(0);
  loadB(0);

  for (int k0 = 0; k0 < K; k0 += 32) {
    __syncthreads();
    storeA(&As[srow * LDT + scol]);
    storeB(&Bs[srow * LDT + scol]);
    __syncthreads();
    if (k0 + 32 < K) {
      loadA(k0 + 32);
      loadB(k0 + 32);
    }
    bf16x8 af[4], bfr[4];
#pragma unroll
    for (int t = 0; t < 4; ++t)
      af[t] = *(const bf16x8*)&As[(wm + t * 16 + l15) * LDT + l4 * 8];
#pragma unroll
    for (int t = 0; t < 4; ++t)
      bfr[t] = *(const bf16x8*)&Bs[(wn + t * 16 + l15) * LDT + l4 * 8];
#pragma unroll
    for (int mt = 0; mt < 4; ++mt)
#pragma unroll
      for (int nt = 0; nt < 4; ++nt)
        acc[mt][nt] = __builtin_amdgcn_mfma_f32_16x16x32_bf16(af[mt], bfr[nt], acc[mt][nt], 0, 0, 0);
  }

  // C/D layout: col = lane&15, row = (lane>>4)*4 + r  (m89-verified)
#pragma unroll
  for (int mt = 0; mt < 4; ++mt)
#pragma unroll
    for (int nt = 0; nt < 4; ++nt) {
      const int row = bm + wm + mt * 16 + l4 * 4;
      const int col = bn + wn + nt * 16 + l15;
#pragma unroll
      for (int r = 0; r < 4; ++r) {
        if constexpr (MODE == 0) {
          if constexpr (sizeof(TC) == 4)
            C[(size_t)(row + r) * N + col] = acc[mt][nt][r];
          else
            C[(size_t)(row + r) * N + col] = f2bf(acc[mt][nt][r]);
        } else {
          // QKV split epilogue (TC = u16). Region is block-uniform.
          u16* Qb = (u16*)C;
          u16* K4 = Qb + 16777216;
          u16* Vb = Qb + 33554432;
          const int rr = row + r;
          const u16 v = f2bf(acc[mt][nt][r]);
          if (col < 1024) {
            Qb[(size_t)rr * 1024 + col] = v;
          } else if (col < 2048) {
            const int d = col - 1024;
            const int b_ = rr >> 12, s = rr & 4095;
            const size_t idx = ((size_t)((b_ * 256 + (s >> 4)) * 32 + (d >> 5))) * 512 +
                               (size_t)((((d >> 3) & 3) * 16 + (s & 15)) * 8 + (d & 7));
            K4[idx] = v;
          } else {
            Vb[(size_t)rr * 1024 + (col - 2048)] = v;
          }
        }
      }
    }
}

// ---------------------------------------------------------------------------
// V4[b][c>>4][s>>5][lane][8] <- Vb[b*4096+s][c]   (64x64 LDS tiles, bf16)
// (lane = ((s>>3)&3)*16 + (c&15), elem j = s&7)
// ---------------------------------------------------------------------------
__global__ __launch_bounds__(256) void transpose_v4(const u16* __restrict__ Vb,
                                                    u16* __restrict__ V4) {
  __shared__ u16 Ts[64][72];
  const int b = blockIdx.z;
  const int s0 = blockIdx.x * 64, c0 = blockIdx.y * 64;
  const int tid = threadIdx.x;
#pragma unroll
  for (int i = 0; i < 2; ++i) {
    const int k = tid + 256 * i;
    const int sr = k >> 3, c8 = (k & 7) * 8;
    uint4 val = *(const uint4*)(Vb + ((size_t)(b * 4096 + s0 + sr)) * 1024 + c0 + c8);
    const u16* e = (const u16*)&val;
#pragma unroll
    for (int j = 0; j < 8; ++j) Ts[c8 + j][sr] = e[j];
  }
  __syncthreads();
#pragma unroll
  for (int i = 0; i < 2; ++i) {
    const int k = tid + 256 * i;
    const int cr = k >> 3, s8 = (k & 7) * 8;
    uint4 val = *(const uint4*)&Ts[cr][s8];
    const int c = c0 + cr, s = s0 + s8;
    const int lane = (((s >> 3) & 3) << 4) + (c & 15);
    const size_t idx = ((size_t)((b * 64 + (c >> 4)) * 128 + (s >> 5))) * 512 + lane * 8;
    *(uint4*)(V4 + idx) = val;
  }
}

// ---------------------------------------------------------------------------
// Flash attention v7 (bf16 internal). 512 thr (8 waves). Wave w = D-slice
// [w*128, w*128+128). Q-tile 32 rows; key tiles of 32 (full K=32 MFMA).
// Grid 512: block c (c<256) -> Q-tile ii, asc key sweep; block c+256 ->
// Q-tile 127-ii, desc sweep. K/V fragments via single coalesced 1KB loads
// from fragment-major K4/V4. K regs double-buffered; V issued at iter top.
// S 8-way cross-wave reduce via swizzled Sred (<=2-way banks both sides).
// ---------------------------------------------------------------------------
__global__ __launch_bounds__(512, 2) void flash_attn(const u16* __restrict__ Qb,
                                                     const u16* __restrict__ K4,
                                                     const u16* __restrict__ V4,
                                                     u16* __restrict__ ao) {
  __shared__ float Sred[8][32][40];  // [wave][row][col^swz], stride 40 floats
  __shared__ u16 P[32][40];          // P tile bf16, row stride 40
  __shared__ float Al[32];           // alpha / inv-l broadcast

  const int tid = threadIdx.x;
  const int lane = tid & 63;
  const int ds = tid >> 6;           // wave id / D-slice
  const int l15 = lane & 15, l4 = lane >> 4;
  const int lane8 = lane * 8;
  const int b = blockIdx.x & 3;
  const int ii = (blockIdx.x >> 2) & 63;  // pair index, 0..63
  const int half = blockIdx.x >> 8;       // 0: tile ii (asc), 1: tile 127-ii (desc)
  const size_t base = (size_t)b * 4096;
  const int srow = ds * 4 + l4;      // softmax-owned row (one per thread)
  const int rswz = (ds & 3) << 3;    // read swizzle
  const int wswz = l4 << 3;          // write swizzle

  const int qt = half ? (127 - ii) : ii;  // 32-row Q-tile index
  const int t0 = qt * 32;

  // Q fragments (A-layout): rows t0+rg*16+l15, cols ds*128+kb*32+l4*8
  bf16x8 qf[2][4];
#pragma unroll
  for (int rg = 0; rg < 2; ++rg)
#pragma unroll
    for (int kb = 0; kb < 4; ++kb)
      qf[rg][kb] = *(const bf16x8*)(Qb + (base + t0 + rg * 16 + l15) * 1024 +
                                    ds * 128 + kb * 32 + l4 * 8);

  f32x4 acc[2][8] = {};              // O[rg 16-rows][nt 16-cols of this D-slice]
  float m_run = -1e30f;
  float l_run = 0.0f;

  // K-fragment double buffer (coalesced from K4).
  bf16x8 kcur[8], knxt[8];
  {
    const int s0p = half ? t0 : 0;   // first tile of this half's sweep
    const size_t kb0 = ((size_t)((b * 256 + (s0p >> 4)) * 32 + ds * 4)) * 512 + lane8;
#pragma unroll
    for (int nt = 0; nt < 2; ++nt)
#pragma unroll
      for (int kb = 0; kb < 4; ++kb)
        kcur[nt * 4 + kb] = *(const bf16x8*)(K4 + kb0 + nt * 16384 + kb * 512);
  }

  const int n_tiles = qt + 1;
  for (int j = 0; j < n_tiles; ++j) {
    const int it = half ? (qt - j) : j;       // asc in half 0, desc in half 1
    const int s0 = it * 32;
    const int itn = half ? (it > 0 ? it - 1 : 0) : (it < qt ? it + 1 : qt);
    const int s0n = itn * 32;

    // --- issue V loads (current tile) + K loads (next tile), all coalesced ---
    bf16x8 vf[8];
    {
      const size_t vb0 = ((size_t)((b * 64 + ds * 8) * 128 + (s0 >> 5))) * 512 + lane8;
#pragma unroll
      for (int nt = 0; nt < 8; ++nt)
        vf[nt] = *(const bf16x8*)(V4 + vb0 + nt * 65536);
    }
    {
      const size_t kbn = ((size_t)((b * 256 + (s0n >> 4)) * 32 + ds * 4)) * 512 + lane8;
#pragma unroll
      for (int nt = 0; nt < 2; ++nt)
#pragma unroll
        for (int kb = 0; kb < 4; ++kb)
          knxt[nt * 4 + kb] = *(const bf16x8*)(K4 + kbn + nt * 16384 + kb * 512);
    }

    // --- QK^T partial over this wave's D-slice: S[32][32] ---
    f32x4 sp[2][2] = {};
#pragma unroll
    for (int kb = 0; kb < 4; ++kb)
#pragma unroll
      for (int nt = 0; nt < 2; ++nt)
#pragma unroll
        for (int rg = 0; rg < 2; ++rg)
          sp[rg][nt] = __builtin_amdgcn_mfma_f32_16x16x32_bf16(qf[rg][kb], kcur[nt * 4 + kb],
                                                               sp[rg][nt], 0, 0, 0);
#pragma unroll
    for (int rg = 0; rg < 2; ++rg)
#pragma unroll
      for (int nt = 0; nt < 2; ++nt)
#pragma unroll
        for (int r = 0; r < 4; ++r)
          Sred[ds][rg * 16 + l4 * 4 + r][(nt * 16 + l15) ^ wswz] = sp[rg][nt][r];
    lds_barrier();

    // --- reduce across waves + online softmax (1 row/thread, 2 cols/lane) ---
    {
      float sa = 0.0f, sb = 0.0f;
#pragma unroll
      for (int w2 = 0; w2 < 8; ++w2) {
        sa += Sred[w2][srow][l15 ^ rswz];
        sb += Sred[w2][srow][(l15 + 16) ^ rswz];
      }
      sa *= 0.03125f;  // 1/sqrt(1024)
      sb *= 0.03125f;
      if (s0 + l15 > t0 + srow) sa = -1e30f;        // causal mask
      if (s0 + l15 + 16 > t0 + srow) sb = -1e30f;
      float mt_ = fmaxf(sa, sb);
      mt_ = fmaxf(mt_, __shfl_xor(mt_, 1));
      mt_ = fmaxf(mt_, __shfl_xor(mt_, 2));
      mt_ = fmaxf(mt_, __shfl_xor(mt_, 4));
      mt_ = fmaxf(mt_, __shfl_xor(mt_, 8));
      const float mn = fmaxf(m_run, mt_);
      const float al = __expf(m_run - mn);
      m_run = mn;
      const float pa = __expf(sa - mn);
      const float pb = __expf(sb - mn);
      float ls = pa + pb;
      ls += __shfl_xor(ls, 1);
      ls += __shfl_xor(ls, 2);
      ls += __shfl_xor(ls, 4);
      ls += __shfl_xor(ls, 8);
      l_run = al * l_run + ls;
      P[srow][l15] = f2bf(pa);
      P[srow][l15 + 16] = f2bf(pb);
      Al[srow] = al;                 // 16-lane duplicate write, benign
    }
    lds_barrier();

    // --- rescale O (skipped when no row max moved) ---
    float av[2][4];
    int need = 0;
#pragma unroll
    for (int rg = 0; rg < 2; ++rg)
#pragma unroll
      for (int r = 0; r < 4; ++r) {
        av[rg][r] = Al[rg * 16 + l4 * 4 + r];
        need |= (av[rg][r] != 1.0f) ? 1 : 0;
      }
    if (__any(need)) {
#pragma unroll
      for (int rg = 0; rg < 2; ++rg)
#pragma unroll
        for (int nt = 0; nt < 8; ++nt)
#pragma unroll
          for (int r = 0; r < 4; ++r) acc[rg][nt][r] *= av[rg][r];
    }

    // --- PV: O += P[32,32] @ V[32, D-slice]  (full K=32 MFMA) ---
    bf16x8 pf[2];
#pragma unroll
    for (int rg = 0; rg < 2; ++rg)
      pf[rg] = *(const bf16x8*)&P[rg * 16 + l15][l4 * 8];
#pragma unroll
    for (int nt = 0; nt < 8; ++nt)
#pragma unroll
      for (int rg = 0; rg < 2; ++rg)
        acc[rg][nt] = __builtin_amdgcn_mfma_f32_16x16x32_bf16(pf[rg], vf[nt], acc[rg][nt], 0, 0, 0);

    // --- rotate K double buffer ---
#pragma unroll
    for (int q8 = 0; q8 < 8; ++q8) kcur[q8] = knxt[q8];
  }

  // --- epilogue: O / l, store bf16 ---
  __syncthreads();
  if (l15 == 0) Al[srow] = 1.0f / l_run;
  __syncthreads();
  float iv[2][4];
#pragma unroll
  for (int rg = 0; rg < 2; ++rg)
#pragma unroll
    for (int r = 0; r < 4; ++r) iv[rg][r] = Al[rg * 16 + l4 * 4 + r];
#pragma unroll
  for (int rg = 0; rg < 2; ++rg)
#pragma unroll
    for (int nt = 0; nt < 8; ++nt) {
      const size_t rbase = (base + t0 + rg * 16 + l4 * 4) * 1024 + ds * 128 + nt * 16 + l15;
#pragma unroll
      for (int r = 0; r < 4; ++r)
        ao[rbase + (size_t)r * 1024] = f2bf(acc[rg][nt][r] * iv[rg][r]);
    }
}

// ---------------------------------------------------------------------------
extern "C" void kernel_launch(void* const* d_in, const int* in_sizes, int n_in,
                              void* d_out, int out_size, void* d_ws, size_t ws_size,
                              hipStream_t stream) {
  const float* x     = (const float*)d_in[0];   // [4,4096,1024] fp32
  // d_in[1] = causal mask: ignored (computed analytically)
  const float* w_qkv = (const float*)d_in[2];   // [3072,1024] fp32
  const float* w_out = (const float*)d_in[3];   // [1024,1024] fp32
  float* out = (float*)d_out;                   // [4,4096,1024] fp32

  u16* ws  = (u16*)d_ws;
  u16* Qb  = ws;                    // 16384x1024
  u16* K4p = ws + 16777216;         // fragment-major K
  u16* Vb  = ws + 33554432;         // 16384x1024 (V row-major staging)
  u16* V4p = ws + 50331648;         // fragment-major V
  u16* aop = ws + 67108864;         // 16384x1024 attention output
  u16* xb  = aop;                   // bf16 x, SHARES ao slot (dead before flash)
  u16* wqb = V4p;                   // bf16 w_qkv, FRONT of V4 slot (dead before transpose)

  cvt_bf16<<<dim3(8192), 256, 0, stream>>>(x, xb, 2097152);      // 16384*1024/8
  cvt_bf16<<<dim3(1536), 256, 0, stream>>>(w_qkv, wqb, 393216);  // 3072*1024/8
  gemm_bt<u16, u16, u16, 1><<<dim3(24, 128), 256, 0, stream>>>(xb, wqb, Qb, 16384, 3072, 1024);
  transpose_v4<<<dim3(64, 16, 4), 256, 0, stream>>>(Vb, V4p);
  flash_attn<<<dim3(512), 512, 0, stream>>>(Qb, K4p, V4p, aop);
  gemm_bt<u16, float, float, 0><<<dim3(8, 128), 256, 0, stream>>>(aop, w_out, out, 16384, 1024, 1024);
}

// Round 9
// 735.329 us; speedup vs baseline: 1.3274x; 1.3274x over previous
//
#include <hip/hip_runtime.h>

// SingleHeadAttention: B=4, T=4096, C=1024, causal. fp32 in/out, bf16 MFMA internally.
// Pipeline: [cvt x,w_qkv] -> [gemm qkv -> Qb,K4,Vb] -> [transpose_v4 Vb->V4]
//           -> [cvt w_out] -> [flash] -> [gemm out]
// ws (u16 elems): Qb[16M] | K4[16M] | Vb[16M] | V4[16M] | ao[16M] = 167.8 MB
//   xb aliases ao slot (dead before flash); wqb aliases V4 front (dead before
//   transpose_v4); wob aliases Vb front (dead after transpose_v4).
//
// v9 = v8 + LDS-staged VECTORIZED GEMM epilogues. v8 counters: qkv gemm wrote
// 739 MB / fetched 184 MB HBM (ideal 105/45) -> 100% HBM-bound at 2 TB/s from
// per-lane 2B scattered stores (write-allocate RMW + partial sectors). Now:
// C tile staged in LDS, stored as uint4/float4 bursts; K region stored
// directly in K4 fragment order (64 lanes = one contiguous 1KB fragment).
// v7 (verified): fragment-major K4/V4 -> coalesced flash operand loads
// (flash 524->289 us). Causal pairing + asc/desc sweeps keep K/V L3-resident.

typedef unsigned short u16;
typedef float f32x4 __attribute__((ext_vector_type(4)));
typedef __bf16 bf16x8 __attribute__((ext_vector_type(8)));

__device__ __forceinline__ u16 f2bf(float f) {
  __bf16 h = (__bf16)f;
  return __builtin_bit_cast(u16, h);
}

// LDS-only barrier: drain own LDS ops, sync; global loads stay in flight.
__device__ __forceinline__ void lds_barrier() {
  asm volatile("s_waitcnt lgkmcnt(0)" ::: "memory");
  __builtin_amdgcn_s_barrier();
}

// ---------------------------------------------------------------------------
// fp32 -> bf16, 8 elems/thread (2x float4 in, 1x uint4 out).
// ---------------------------------------------------------------------------
__global__ __launch_bounds__(256) void cvt_bf16(const float* __restrict__ src,
                                                u16* __restrict__ dst, int n8) {
  const int i = blockIdx.x * 256 + threadIdx.x;
  if (i < n8) {
    float4 a = ((const float4*)src)[2 * i];
    float4 b = ((const float4*)src)[2 * i + 1];
    u16 t[8] = {f2bf(a.x), f2bf(a.y), f2bf(a.z), f2bf(a.w),
                f2bf(b.x), f2bf(b.y), f2bf(b.z), f2bf(b.w)};
    ((uint4*)dst)[i] = *(const uint4*)t;
  }
}

// ---------------------------------------------------------------------------
// C[M][N] = A[M][K] @ B[N][K]^T  (bf16 MFMA, fp32 accumulate). bf16 operands.
// MODE 0: row-major fp32 C, LDS-staged float4 stores (2 half-tile passes).
// MODE 1: QKV split; C = ws base. cols 0..1023 -> Qb row-major; 1024..2047 ->
//   K4 fragment-major (uint4, 1KB-contiguous per 64 lanes); 2048..3071 -> Vb
//   row-major. All stores 16 B, LDS-staged.
// 128x128 tile, BK=32, 4 waves 2x2, each wave 64x64 via 4x4 MFMA 16x16x32.
// ---------------------------------------------------------------------------
template <typename TA, typename TB, typename TC, int MODE>
__global__ __launch_bounds__(256) void gemm_bt(const TA* __restrict__ A,
                                               const TB* __restrict__ B,
                                               TC* __restrict__ C,
                                               int M, int N, int K) {
  constexpr int LDT = 40;
  __shared__ u16 As[128 * LDT];
  __shared__ u16 Bs[128 * LDT];
  __shared__ __align__(16) char Craw[34816];  // 128x136 u16 | 64x132 f32
  const int tid = threadIdx.x;
  const int lane = tid & 63, wv = tid >> 6;
  const int l15 = lane & 15, l4 = lane >> 4;
  const int bm = blockIdx.y * 128, bn = blockIdx.x * 128;
  const int wm = (wv >> 1) * 64, wn = (wv & 1) * 64;
  const int srow = tid >> 1, scol = (tid & 1) * 16;  // each thread stages 16 elems of one row
  const TA* ag = A + (size_t)(bm + srow) * K + scol;
  const TB* bg = B + (size_t)(bn + srow) * K + scol;

  uint4 pau[2], pbu[2];
  auto loadA = [&](int off) {
    pau[0] = *(const uint4*)((const u16*)ag + off);
    pau[1] = *(const uint4*)((const u16*)ag + off + 8);
  };
  auto loadB = [&](int off) {
    pbu[0] = *(const uint4*)((const u16*)bg + off);
    pbu[1] = *(const uint4*)((const u16*)bg + off + 8);
  };

  f32x4 acc[4][4] = {};
  loadA(0);
  loadB(0);

  for (int k0 = 0; k0 < K; k0 += 32) {
    __syncthreads();
    *(uint4*)&As[srow * LDT + scol] = pau[0];
    *(uint4*)&As[srow * LDT + scol + 8] = pau[1];
    *(uint4*)&Bs[srow * LDT + scol] = pbu[0];
    *(uint4*)&Bs[srow * LDT + scol + 8] = pbu[1];
    __syncthreads();
    if (k0 + 32 < K) {  // prefetch next tile; overlaps with MFMA below
      loadA(k0 + 32);
      loadB(k0 + 32);
    }
    bf16x8 af[4], bfr[4];
#pragma unroll
    for (int t = 0; t < 4; ++t)
      af[t] = *(const bf16x8*)&As[(wm + t * 16 + l15) * LDT + l4 * 8];
#pragma unroll
    for (int t = 0; t < 4; ++t)
      bfr[t] = *(const bf16x8*)&Bs[(wn + t * 16 + l15) * LDT + l4 * 8];
#pragma unroll
    for (int mt = 0; mt < 4; ++mt)
#pragma unroll
      for (int nt = 0; nt < 4; ++nt)
        acc[mt][nt] = __builtin_amdgcn_mfma_f32_16x16x32_bf16(af[mt], bfr[nt], acc[mt][nt], 0, 0, 0);
  }

  // ---- epilogue: LDS-staged vectorized stores ----
  // acc C/D layout: col = lane&15, row = (lane>>4)*4 + r  (m89-verified)
  if constexpr (MODE == 1) {
    u16(*Cs)[136] = (u16(*)[136])Craw;
    __syncthreads();
#pragma unroll
    for (int mt = 0; mt < 4; ++mt)
#pragma unroll
      for (int nt = 0; nt < 4; ++nt)
#pragma unroll
        for (int r = 0; r < 4; ++r)
          Cs[wm + mt * 16 + l4 * 4 + r][wn + nt * 16 + l15] = f2bf(acc[mt][nt][r]);
    __syncthreads();
    const int region = bn >> 10;  // bn=blk*128: 0..1023 Q, 1024..2047 K, else V
    if (region != 1) {
      u16* dst = (region == 0) ? (u16*)C : ((u16*)C + 33554432);
      const int cb = bn & 1023;
#pragma unroll
      for (int i = 0; i < 8; ++i) {
        const int row = i * 16 + (tid >> 4);
        const int c8 = (tid & 15) * 8;
        uint4 v = *(const uint4*)&Cs[row][c8];
        *(uint4*)(dst + (size_t)(bm + row) * 1024 + cb + c8) = v;
      }
    } else {
      u16* K4 = (u16*)C + 16777216;
      const int b_ = blockIdx.y >> 5;           // 32 row-blocks per batch
      const int s16b = (blockIdx.y & 31) * 8;   // in-batch s16 base
      const int d32b = ((bn - 1024) >> 5);      // global d32 base (4 per block)
      const int l63 = tid & 63;
#pragma unroll
      for (int p = 0; p < 8; ++p) {
        const int fid = p * 4 + (tid >> 6);     // 32 fragments per tile
        const int s16l = fid >> 2, d32l = fid & 3;
        uint4 v = *(const uint4*)&Cs[s16l * 16 + (l63 & 15)][d32l * 32 + (l63 >> 4) * 8];
        *(uint4*)(K4 + ((size_t)((b_ * 256 + s16b + s16l) * 32 + d32b + d32l)) * 512 + l63 * 8) = v;
      }
    }
  } else {
    float(*Csf)[132] = (float(*)[132])Craw;
#pragma unroll 1
    for (int h = 0; h < 2; ++h) {
      __syncthreads();
      if ((wv >> 1) == h) {
#pragma unroll
        for (int mt = 0; mt < 4; ++mt)
#pragma unroll
          for (int nt = 0; nt < 4; ++nt)
#pragma unroll
            for (int r = 0; r < 4; ++r)
              Csf[mt * 16 + l4 * 4 + r][wn + nt * 16 + l15] = acc[mt][nt][r];
      }
      __syncthreads();
#pragma unroll
      for (int i = 0; i < 8; ++i) {
        const int k = i * 256 + tid;
        const int row = k >> 5, cg = (k & 31) * 4;
        float4 v = *(const float4*)&Csf[row][cg];
        *(float4*)((float*)C + (size_t)(bm + h * 64 + row) * N + bn + cg) = v;
      }
    }
  }
}

// ---------------------------------------------------------------------------
// V4[b][c>>4][s>>5][lane][8] <- Vb[b*4096+s][c]   (64x64 LDS tiles, bf16)
// (lane = ((s>>3)&3)*16 + (c&15), elem j = s&7)
// ---------------------------------------------------------------------------
__global__ __launch_bounds__(256) void transpose_v4(const u16* __restrict__ Vb,
                                                    u16* __restrict__ V4) {
  __shared__ u16 Ts[64][72];
  const int b = blockIdx.z;
  const int s0 = blockIdx.x * 64, c0 = blockIdx.y * 64;
  const int tid = threadIdx.x;
#pragma unroll
  for (int i = 0; i < 2; ++i) {
    const int k = tid + 256 * i;
    const int sr = k >> 3, c8 = (k & 7) * 8;
    uint4 val = *(const uint4*)(Vb + ((size_t)(b * 4096 + s0 + sr)) * 1024 + c0 + c8);
    const u16* e = (const u16*)&val;
#pragma unroll
    for (int j = 0; j < 8; ++j) Ts[c8 + j][sr] = e[j];
  }
  __syncthreads();
#pragma unroll
  for (int i = 0; i < 2; ++i) {
    const int k = tid + 256 * i;
    const int cr = k >> 3, s8 = (k & 7) * 8;
    uint4 val = *(const uint4*)&Ts[cr][s8];
    const int c = c0 + cr, s = s0 + s8;
    const int lane = (((s >> 3) & 3) << 4) + (c & 15);
    const size_t idx = ((size_t)((b * 64 + (c >> 4)) * 128 + (s >> 5))) * 512 + lane * 8;
    *(uint4*)(V4 + idx) = val;
  }
}

// ---------------------------------------------------------------------------
// Flash attention (v7 structure, verified). 512 thr (8 waves). Wave w =
// D-slice [w*128,w*128+128). Q-tile 32 rows; key tiles of 32 (full K=32 MFMA).
// Grid 512: block c (c<256) -> Q-tile ii, asc key sweep; block c+256 ->
// Q-tile 127-ii, desc sweep. K/V fragments via single coalesced 1KB loads
// from fragment-major K4/V4. K regs double-buffered; V issued at iter top.
// S 8-way cross-wave reduce via swizzled Sred (<=2-way banks both sides).
// ---------------------------------------------------------------------------
__global__ __launch_bounds__(512, 2) void flash_attn(const u16* __restrict__ Qb,
                                                     const u16* __restrict__ K4,
                                                     const u16* __restrict__ V4,
                                                     u16* __restrict__ ao) {
  __shared__ float Sred[8][32][40];  // [wave][row][col^swz], stride 40 floats
  __shared__ u16 P[32][40];          // P tile bf16, row stride 40
  __shared__ float Al[32];           // alpha / inv-l broadcast

  const int tid = threadIdx.x;
  const int lane = tid & 63;
  const int ds = tid >> 6;           // wave id / D-slice
  const int l15 = lane & 15, l4 = lane >> 4;
  const int lane8 = lane * 8;
  const int b = blockIdx.x & 3;
  const int ii = (blockIdx.x >> 2) & 63;  // pair index, 0..63
  const int half = blockIdx.x >> 8;       // 0: tile ii (asc), 1: tile 127-ii (desc)
  const size_t base = (size_t)b * 4096;
  const int srow = ds * 4 + l4;      // softmax-owned row (one per thread)
  const int rswz = (ds & 3) << 3;    // read swizzle
  const int wswz = l4 << 3;          // write swizzle

  const int qt = half ? (127 - ii) : ii;  // 32-row Q-tile index
  const int t0 = qt * 32;

  // Q fragments (A-layout): rows t0+rg*16+l15, cols ds*128+kb*32+l4*8
  bf16x8 qf[2][4];
#pragma unroll
  for (int rg = 0; rg < 2; ++rg)
#pragma unroll
    for (int kb = 0; kb < 4; ++kb)
      qf[rg][kb] = *(const bf16x8*)(Qb + (base + t0 + rg * 16 + l15) * 1024 +
                                    ds * 128 + kb * 32 + l4 * 8);

  f32x4 acc[2][8] = {};              // O[rg 16-rows][nt 16-cols of this D-slice]
  float m_run = -1e30f;
  float l_run = 0.0f;

  // K-fragment double buffer (coalesced from K4).
  bf16x8 kcur[8], knxt[8];
  {
    const int s0p = half ? t0 : 0;   // first tile of this half's sweep
    const size_t kb0 = ((size_t)((b * 256 + (s0p >> 4)) * 32 + ds * 4)) * 512 + lane8;
#pragma unroll
    for (int nt = 0; nt < 2; ++nt)
#pragma unroll
      for (int kb = 0; kb < 4; ++kb)
        kcur[nt * 4 + kb] = *(const bf16x8*)(K4 + kb0 + nt * 16384 + kb * 512);
  }

  const int n_tiles = qt + 1;
  for (int j = 0; j < n_tiles; ++j) {
    const int it = half ? (qt - j) : j;       // asc in half 0, desc in half 1
    const int s0 = it * 32;
    const int itn = half ? (it > 0 ? it - 1 : 0) : (it < qt ? it + 1 : qt);
    const int s0n = itn * 32;

    // --- issue V loads (current tile) + K loads (next tile), all coalesced ---
    bf16x8 vf[8];
    {
      const size_t vb0 = ((size_t)((b * 64 + ds * 8) * 128 + (s0 >> 5))) * 512 + lane8;
#pragma unroll
      for (int nt = 0; nt < 8; ++nt)
        vf[nt] = *(const bf16x8*)(V4 + vb0 + nt * 65536);
    }
    {
      const size_t kbn = ((size_t)((b * 256 + (s0n >> 4)) * 32 + ds * 4)) * 512 + lane8;
#pragma unroll
      for (int nt = 0; nt < 2; ++nt)
#pragma unroll
        for (int kb = 0; kb < 4; ++kb)
          knxt[nt * 4 + kb] = *(const bf16x8*)(K4 + kbn + nt * 16384 + kb * 512);
    }

    // --- QK^T partial over this wave's D-slice: S[32][32] ---
    f32x4 sp[2][2] = {};
#pragma unroll
    for (int kb = 0; kb < 4; ++kb)
#pragma unroll
      for (int nt = 0; nt < 2; ++nt)
#pragma unroll
        for (int rg = 0; rg < 2; ++rg)
          sp[rg][nt] = __builtin_amdgcn_mfma_f32_16x16x32_bf16(qf[rg][kb], kcur[nt * 4 + kb],
                                                               sp[rg][nt], 0, 0, 0);
#pragma unroll
    for (int rg = 0; rg < 2; ++rg)
#pragma unroll
      for (int nt = 0; nt < 2; ++nt)
#pragma unroll
        for (int r = 0; r < 4; ++r)
          Sred[ds][rg * 16 + l4 * 4 + r][(nt * 16 + l15) ^ wswz] = sp[rg][nt][r];
    lds_barrier();

    // --- reduce across waves + online softmax (1 row/thread, 2 cols/lane) ---
    {
      float sa = 0.0f, sb = 0.0f;
#pragma unroll
      for (int w2 = 0; w2 < 8; ++w2) {
        sa += Sred[w2][srow][l15 ^ rswz];
        sb += Sred[w2][srow][(l15 + 16) ^ rswz];
      }
      sa *= 0.03125f;  // 1/sqrt(1024)
      sb *= 0.03125f;
      if (s0 + l15 > t0 + srow) sa = -1e30f;        // causal mask
      if (s0 + l15 + 16 > t0 + srow) sb = -1e30f;
      float mt_ = fmaxf(sa, sb);
      mt_ = fmaxf(mt_, __shfl_xor(mt_, 1));
      mt_ = fmaxf(mt_, __shfl_xor(mt_, 2));
      mt_ = fmaxf(mt_, __shfl_xor(mt_, 4));
      mt_ = fmaxf(mt_, __shfl_xor(mt_, 8));
      const float mn = fmaxf(m_run, mt_);
      const float al = __expf(m_run - mn);
      m_run = mn;
      const float pa = __expf(sa - mn);
      const float pb = __expf(sb - mn);
      float ls = pa + pb;
      ls += __shfl_xor(ls, 1);
      ls += __shfl_xor(ls, 2);
      ls += __shfl_xor(ls, 4);
      ls += __shfl_xor(ls, 8);
      l_run = al * l_run + ls;
      P[srow][l15] = f2bf(pa);
      P[srow][l15 + 16] = f2bf(pb);
      Al[srow] = al;                 // 16-lane duplicate write, benign
    }
    lds_barrier();

    // --- rescale O (skipped when no row max moved) ---
    float av[2][4];
    int need = 0;
#pragma unroll
    for (int rg = 0; rg < 2; ++rg)
#pragma unroll
      for (int r = 0; r < 4; ++r) {
        av[rg][r] = Al[rg * 16 + l4 * 4 + r];
        need |= (av[rg][r] != 1.0f) ? 1 : 0;
      }
    if (__any(need)) {
#pragma unroll
      for (int rg = 0; rg < 2; ++rg)
#pragma unroll
        for (int nt = 0; nt < 8; ++nt)
#pragma unroll
          for (int r = 0; r < 4; ++r) acc[rg][nt][r] *= av[rg][r];
    }

    // --- PV: O += P[32,32] @ V[32, D-slice]  (full K=32 MFMA) ---
    bf16x8 pf[2];
#pragma unroll
    for (int rg = 0; rg < 2; ++rg)
      pf[rg] = *(const bf16x8*)&P[rg * 16 + l15][l4 * 8];
#pragma unroll
    for (int nt = 0; nt < 8; ++nt)
#pragma unroll
      for (int rg = 0; rg < 2; ++rg)
        acc[rg][nt] = __builtin_amdgcn_mfma_f32_16x16x32_bf16(pf[rg], vf[nt], acc[rg][nt], 0, 0, 0);

    // --- rotate K double buffer ---
#pragma unroll
    for (int q8 = 0; q8 < 8; ++q8) kcur[q8] = knxt[q8];
  }

  // --- epilogue: O / l, store bf16 ---
  __syncthreads();
  if (l15 == 0) Al[srow] = 1.0f / l_run;
  __syncthreads();
  float iv[2][4];
#pragma unroll
  for (int rg = 0; rg < 2; ++rg)
#pragma unroll
    for (int r = 0; r < 4; ++r) iv[rg][r] = Al[rg * 16 + l4 * 4 + r];
#pragma unroll
  for (int rg = 0; rg < 2; ++rg)
#pragma unroll
    for (int nt = 0; nt < 8; ++nt) {
      const size_t rbase = (base + t0 + rg * 16 + l4 * 4) * 1024 + ds * 128 + nt * 16 + l15;
#pragma unroll
      for (int r = 0; r < 4; ++r)
        ao[rbase + (size_t)r * 1024] = f2bf(acc[rg][nt][r] * iv[rg][r]);
    }
}

// ---------------------------------------------------------------------------
extern "C" void kernel_launch(void* const* d_in, const int* in_sizes, int n_in,
                              void* d_out, int out_size, void* d_ws, size_t ws_size,
                              hipStream_t stream) {
  const float* x     = (const float*)d_in[0];   // [4,4096,1024] fp32
  // d_in[1] = causal mask: ignored (computed analytically)
  const float* w_qkv = (const float*)d_in[2];   // [3072,1024] fp32
  const float* w_out = (const float*)d_in[3];   // [1024,1024] fp32
  float* out = (float*)d_out;                   // [4,4096,1024] fp32

  u16* ws  = (u16*)d_ws;
  u16* Qb  = ws;                    // 16384x1024 row-major
  u16* K4p = ws + 16777216;         // fragment-major K
  u16* Vb  = ws + 33554432;         // 16384x1024 row-major (V staging)
  u16* V4p = ws + 50331648;         // fragment-major V
  u16* aop = ws + 67108864;         // 16384x1024 attention output
  u16* xb  = aop;                   // bf16 x, aliases ao (dead before flash)
  u16* wqb = V4p;                   // bf16 w_qkv, aliases V4 front (dead before transpose)
  u16* wob = Vb;                    // bf16 w_out, aliases Vb front (dead after transpose)

  cvt_bf16<<<dim3(8192), 256, 0, stream>>>(x, xb, 2097152);      // 16384*1024/8
  cvt_bf16<<<dim3(1536), 256, 0, stream>>>(w_qkv, wqb, 393216);  // 3072*1024/8
  gemm_bt<u16, u16, u16, 1><<<dim3(24, 128), 256, 0, stream>>>(xb, wqb, Qb, 16384, 3072, 1024);
  transpose_v4<<<dim3(64, 16, 4), 256, 0, stream>>>(Vb, V4p);
  cvt_bf16<<<dim3(512), 256, 0, stream>>>(w_out, wob, 131072);   // 1024*1024/8
  flash_attn<<<dim3(512), 512, 0, stream>>>(Qb, K4p, V4p, aop);
  gemm_bt<u16, u16, float, 0><<<dim3(8, 128), 256, 0, stream>>>(aop, wob, out, 16384, 1024, 1024);
}

// Round 10
// 589.844 us; speedup vs baseline: 1.6548x; 1.2466x over previous
//
#include <hip/hip_runtime.h>

// SingleHeadAttention: B=4, T=4096, C=1024, causal. fp32 in/out, bf16 MFMA internally.
// Pipeline: [cvt x,w_qkv] -> [gemm qkv -> Qb,K4,Vb] -> [transpose_v4 Vb->V4]
//           -> [cvt w_out] -> [flash] -> [gemm out]
// ws (u16 elems): Qb[16M] | K4[16M] | Vb[16M] | V4[16M] | ao[16M] = 167.8 MB
//   xb aliases ao slot (dead before flash); wqb aliases V4 front (dead before
//   transpose_v4); wob aliases Vb front (dead after transpose_v4).
//
// v10 = v9 + global_load_lds GEMM staging (m97 ladder rung, +67% measured).
// Staging: linear [128][32] bf16 LDS tiles (no padding -- global_load_lds
// writes wave-uniform base + lane*16B; lane l <-> row 16c+(l>>2), col (l&3)*8
// is exactly offset 8l elems). Double-buffered, ONE __syncthreads per K-step
// (its implicit vmcnt drain publishes the staged buffer); next tile's loads
// are issued right after the barrier and fly across the MFMA body.
// v9 (verified): LDS-staged vectorized epilogues (WRITE_SIZE 739->~100 MB).
// v7 (verified): fragment-major K4/V4 -> coalesced flash loads (524->289 us).

typedef unsigned short u16;
typedef float f32x4 __attribute__((ext_vector_type(4)));
typedef __bf16 bf16x8 __attribute__((ext_vector_type(8)));

__device__ __forceinline__ u16 f2bf(float f) {
  __bf16 h = (__bf16)f;
  return __builtin_bit_cast(u16, h);
}

// LDS-only barrier: drain own LDS ops, sync; global loads stay in flight.
__device__ __forceinline__ void lds_barrier() {
  asm volatile("s_waitcnt lgkmcnt(0)" ::: "memory");
  __builtin_amdgcn_s_barrier();
}

// global -> LDS async copy, 16 B per lane (global_load_lds_dwordx4).
__device__ __forceinline__ void glds16(const u16* g, u16* l) {
  __builtin_amdgcn_global_load_lds((const __attribute__((address_space(1))) void*)g,
                                   (__attribute__((address_space(3))) void*)l, 16, 0, 0);
}

// ---------------------------------------------------------------------------
// fp32 -> bf16, 8 elems/thread (2x float4 in, 1x uint4 out).
// ---------------------------------------------------------------------------
__global__ __launch_bounds__(256) void cvt_bf16(const float* __restrict__ src,
                                                u16* __restrict__ dst, int n8) {
  const int i = blockIdx.x * 256 + threadIdx.x;
  if (i < n8) {
    float4 a = ((const float4*)src)[2 * i];
    float4 b = ((const float4*)src)[2 * i + 1];
    u16 t[8] = {f2bf(a.x), f2bf(a.y), f2bf(a.z), f2bf(a.w),
                f2bf(b.x), f2bf(b.y), f2bf(b.z), f2bf(b.w)};
    ((uint4*)dst)[i] = *(const uint4*)t;
  }
}

// ---------------------------------------------------------------------------
// C[M][N] = A[M][K] @ B[N][K]^T  (bf16 operands via u16, fp32 accumulate).
// Staging: global_load_lds into double-buffered linear [128][32] tiles.
// MODE 0: row-major fp32 C, LDS-staged float4 stores (2 half-tile passes).
// MODE 1: QKV split; C = ws base. cols 0..1023 -> Qb row-major; 1024..2047 ->
//   K4 fragment-major (uint4, 1KB-contiguous per 64 lanes); 2048..3071 -> Vb
//   row-major. All stores 16 B, LDS-staged.
// 128x128 tile, BK=32, 4 waves 2x2, each wave 64x64 via 4x4 MFMA 16x16x32.
// ---------------------------------------------------------------------------
template <typename TC, int MODE>
__global__ __launch_bounds__(256) void gemm_bt(const u16* __restrict__ A,
                                               const u16* __restrict__ B,
                                               TC* __restrict__ C,
                                               int M, int N, int K) {
  // LDS pool: staging Abuf[2][4096] | Bbuf[2][4096] (32 KB), unioned with the
  // epilogue C-stage (<= 34816 B). Staging is dead before the epilogue reuses it.
  __shared__ __align__(16) char pool[36864];
  u16* Asb = (u16*)pool;            // [2][4096]
  u16* Bsb = (u16*)(pool + 16384);  // [2][4096]

  const int tid = threadIdx.x;
  const int lane = tid & 63, wv = tid >> 6;
  const int l15 = lane & 15, l4 = lane >> 4;
  const int bm = blockIdx.y * 128, bn = blockIdx.x * 128;
  const int wm = (wv >> 1) * 64, wn = (wv & 1) * 64;

  // Staging map: wave wv owns 1KB chunks {2wv, 2wv+1} of each tile.
  // Chunk c: lane l -> global (row 16c + (l>>2), col (l&3)*8) == LDS off 8l.
  const int c0 = 2 * wv, c1 = 2 * wv + 1;
  const int gr0 = 16 * c0 + (lane >> 2), gr1 = 16 * c1 + (lane >> 2);
  const int gcol = (lane & 3) * 8;
  const u16* a0 = A + (size_t)(bm + gr0) * K + gcol;
  const u16* a1 = A + (size_t)(bm + gr1) * K + gcol;
  const u16* b0 = B + (size_t)(bn + gr0) * K + gcol;
  const u16* b1 = B + (size_t)(bn + gr1) * K + gcol;

  auto stage = [&](int buf, int k0) {
    glds16(a0 + k0, Asb + buf * 4096 + c0 * 512);
    glds16(a1 + k0, Asb + buf * 4096 + c1 * 512);
    glds16(b0 + k0, Bsb + buf * 4096 + c0 * 512);
    glds16(b1 + k0, Bsb + buf * 4096 + c1 * 512);
  };

  f32x4 acc[4][4] = {};
  int cur = 0;
  stage(0, 0);

  for (int k0 = 0; k0 < K; k0 += 32) {
    __syncthreads();                 // drains own vmcnt -> buf[cur] ready for all
    if (k0 + 32 < K) stage(cur ^ 1, k0 + 32);  // next tile flies over MFMA body
    const u16* Ab = Asb + cur * 4096;
    const u16* Bb = Bsb + cur * 4096;
    bf16x8 af[4], bfr[4];
#pragma unroll
    for (int t = 0; t < 4; ++t)
      af[t] = *(const bf16x8*)&Ab[(wm + t * 16 + l15) * 32 + l4 * 8];
#pragma unroll
    for (int t = 0; t < 4; ++t)
      bfr[t] = *(const bf16x8*)&Bb[(wn + t * 16 + l15) * 32 + l4 * 8];
#pragma unroll
    for (int mt = 0; mt < 4; ++mt)
#pragma unroll
      for (int nt = 0; nt < 4; ++nt)
        acc[mt][nt] = __builtin_amdgcn_mfma_f32_16x16x32_bf16(af[mt], bfr[nt], acc[mt][nt], 0, 0, 0);
    cur ^= 1;
  }

  // ---- epilogue: LDS-staged vectorized stores (v9, verified) ----
  // acc C/D layout: col = lane&15, row = (lane>>4)*4 + r  (m89-verified)
  if constexpr (MODE == 1) {
    u16(*Cs)[136] = (u16(*)[136])pool;
    __syncthreads();
#pragma unroll
    for (int mt = 0; mt < 4; ++mt)
#pragma unroll
      for (int nt = 0; nt < 4; ++nt)
#pragma unroll
        for (int r = 0; r < 4; ++r)
          Cs[wm + mt * 16 + l4 * 4 + r][wn + nt * 16 + l15] = f2bf(acc[mt][nt][r]);
    __syncthreads();
    const int region = bn >> 10;  // bn=blk*128: 0..1023 Q, 1024..2047 K, else V
    if (region != 1) {
      u16* dst = (region == 0) ? (u16*)C : ((u16*)C + 33554432);
      const int cb = bn & 1023;
#pragma unroll
      for (int i = 0; i < 8; ++i) {
        const int row = i * 16 + (tid >> 4);
        const int c8 = (tid & 15) * 8;
        uint4 v = *(const uint4*)&Cs[row][c8];
        *(uint4*)(dst + (size_t)(bm + row) * 1024 + cb + c8) = v;
      }
    } else {
      u16* K4 = (u16*)C + 16777216;
      const int b_ = blockIdx.y >> 5;           // 32 row-blocks per batch
      const int s16b = (blockIdx.y & 31) * 8;   // in-batch s16 base
      const int d32b = ((bn - 1024) >> 5);      // global d32 base (4 per block)
      const int l63 = tid & 63;
#pragma unroll
      for (int p = 0; p < 8; ++p) {
        const int fid = p * 4 + (tid >> 6);     // 32 fragments per tile
        const int s16l = fid >> 2, d32l = fid & 3;
        uint4 v = *(const uint4*)&Cs[s16l * 16 + (l63 & 15)][d32l * 32 + (l63 >> 4) * 8];
        *(uint4*)(K4 + ((size_t)((b_ * 256 + s16b + s16l) * 32 + d32b + d32l)) * 512 + l63 * 8) = v;
      }
    }
  } else {
    float(*Csf)[132] = (float(*)[132])pool;
#pragma unroll 1
    for (int h = 0; h < 2; ++h) {
      __syncthreads();
      if ((wv >> 1) == h) {
#pragma unroll
        for (int mt = 0; mt < 4; ++mt)
#pragma unroll
          for (int nt = 0; nt < 4; ++nt)
#pragma unroll
            for (int r = 0; r < 4; ++r)
              Csf[mt * 16 + l4 * 4 + r][wn + nt * 16 + l15] = acc[mt][nt][r];
      }
      __syncthreads();
#pragma unroll
      for (int i = 0; i < 8; ++i) {
        const int k = i * 256 + tid;
        const int row = k >> 5, cg = (k & 31) * 4;
        float4 v = *(const float4*)&Csf[row][cg];
        *(float4*)((float*)C + (size_t)(bm + h * 64 + row) * N + bn + cg) = v;
      }
    }
  }
}

// ---------------------------------------------------------------------------
// V4[b][c>>4][s>>5][lane][8] <- Vb[b*4096+s][c]   (64x64 LDS tiles, bf16)
// (lane = ((s>>3)&3)*16 + (c&15), elem j = s&7)
// ---------------------------------------------------------------------------
__global__ __launch_bounds__(256) void transpose_v4(const u16* __restrict__ Vb,
                                                    u16* __restrict__ V4) {
  __shared__ u16 Ts[64][72];
  const int b = blockIdx.z;
  const int s0 = blockIdx.x * 64, c0 = blockIdx.y * 64;
  const int tid = threadIdx.x;
#pragma unroll
  for (int i = 0; i < 2; ++i) {
    const int k = tid + 256 * i;
    const int sr = k >> 3, c8 = (k & 7) * 8;
    uint4 val = *(const uint4*)(Vb + ((size_t)(b * 4096 + s0 + sr)) * 1024 + c0 + c8);
    const u16* e = (const u16*)&val;
#pragma unroll
    for (int j = 0; j < 8; ++j) Ts[c8 + j][sr] = e[j];
  }
  __syncthreads();
#pragma unroll
  for (int i = 0; i < 2; ++i) {
    const int k = tid + 256 * i;
    const int cr = k >> 3, s8 = (k & 7) * 8;
    uint4 val = *(const uint4*)&Ts[cr][s8];
    const int c = c0 + cr, s = s0 + s8;
    const int lane = (((s >> 3) & 3) << 4) + (c & 15);
    const size_t idx = ((size_t)((b * 64 + (c >> 4)) * 128 + (s >> 5))) * 512 + lane * 8;
    *(uint4*)(V4 + idx) = val;
  }
}

// ---------------------------------------------------------------------------
// Flash attention (v7 structure, verified). 512 thr (8 waves). Wave w =
// D-slice [w*128,w*128+128). Q-tile 32 rows; key tiles of 32 (full K=32 MFMA).
// Grid 512: block c (c<256) -> Q-tile ii, asc key sweep; block c+256 ->
// Q-tile 127-ii, desc sweep. K/V fragments via single coalesced 1KB loads
// from fragment-major K4/V4. K regs double-buffered; V issued at iter top.
// S 8-way cross-wave reduce via swizzled Sred (<=2-way banks both sides).
// ---------------------------------------------------------------------------
__global__ __launch_bounds__(512, 2) void flash_attn(const u16* __restrict__ Qb,
                                                     const u16* __restrict__ K4,
                                                     const u16* __restrict__ V4,
                                                     u16* __restrict__ ao) {
  __shared__ float Sred[8][32][40];  // [wave][row][col^swz], stride 40 floats
  __shared__ u16 P[32][40];          // P tile bf16, row stride 40
  __shared__ float Al[32];           // alpha / inv-l broadcast

  const int tid = threadIdx.x;
  const int lane = tid & 63;
  const int ds = tid >> 6;           // wave id / D-slice
  const int l15 = lane & 15, l4 = lane >> 4;
  const int lane8 = lane * 8;
  const int b = blockIdx.x & 3;
  const int ii = (blockIdx.x >> 2) & 63;  // pair index, 0..63
  const int half = blockIdx.x >> 8;       // 0: tile ii (asc), 1: tile 127-ii (desc)
  const size_t base = (size_t)b * 4096;
  const int srow = ds * 4 + l4;      // softmax-owned row (one per thread)
  const int rswz = (ds & 3) << 3;    // read swizzle
  const int wswz = l4 << 3;          // write swizzle

  const int qt = half ? (127 - ii) : ii;  // 32-row Q-tile index
  const int t0 = qt * 32;

  // Q fragments (A-layout): rows t0+rg*16+l15, cols ds*128+kb*32+l4*8
  bf16x8 qf[2][4];
#pragma unroll
  for (int rg = 0; rg < 2; ++rg)
#pragma unroll
    for (int kb = 0; kb < 4; ++kb)
      qf[rg][kb] = *(const bf16x8*)(Qb + (base + t0 + rg * 16 + l15) * 1024 +
                                    ds * 128 + kb * 32 + l4 * 8);

  f32x4 acc[2][8] = {};              // O[rg 16-rows][nt 16-cols of this D-slice]
  float m_run = -1e30f;
  float l_run = 0.0f;

  // K-fragment double buffer (coalesced from K4).
  bf16x8 kcur[8], knxt[8];
  {
    const int s0p = half ? t0 : 0;   // first tile of this half's sweep
    const size_t kb0 = ((size_t)((b * 256 + (s0p >> 4)) * 32 + ds * 4)) * 512 + lane8;
#pragma unroll
    for (int nt = 0; nt < 2; ++nt)
#pragma unroll
      for (int kb = 0; kb < 4; ++kb)
        kcur[nt * 4 + kb] = *(const bf16x8*)(K4 + kb0 + nt * 16384 + kb * 512);
  }

  const int n_tiles = qt + 1;
  for (int j = 0; j < n_tiles; ++j) {
    const int it = half ? (qt - j) : j;       // asc in half 0, desc in half 1
    const int s0 = it * 32;
    const int itn = half ? (it > 0 ? it - 1 : 0) : (it < qt ? it + 1 : qt);
    const int s0n = itn * 32;

    // --- issue V loads (current tile) + K loads (next tile), all coalesced ---
    bf16x8 vf[8];
    {
      const size_t vb0 = ((size_t)((b * 64 + ds * 8) * 128 + (s0 >> 5))) * 512 + lane8;
#pragma unroll
      for (int nt = 0; nt < 8; ++nt)
        vf[nt] = *(const bf16x8*)(V4 + vb0 + nt * 65536);
    }
    {
      const size_t kbn = ((size_t)((b * 256 + (s0n >> 4)) * 32 + ds * 4)) * 512 + lane8;
#pragma unroll
      for (int nt = 0; nt < 2; ++nt)
#pragma unroll
        for (int kb = 0; kb < 4; ++kb)
          knxt[nt * 4 + kb] = *(const bf16x8*)(K4 + kbn + nt * 16384 + kb * 512);
    }

    // --- QK^T partial over this wave's D-slice: S[32][32] ---
    f32x4 sp[2][2] = {};
#pragma unroll
    for (int kb = 0; kb < 4; ++kb)
#pragma unroll
      for (int nt = 0; nt < 2; ++nt)
#pragma unroll
        for (int rg = 0; rg < 2; ++rg)
          sp[rg][nt] = __builtin_amdgcn_mfma_f32_16x16x32_bf16(qf[rg][kb], kcur[nt * 4 + kb],
                                                               sp[rg][nt], 0, 0, 0);
#pragma unroll
    for (int rg = 0; rg < 2; ++rg)
#pragma unroll
      for (int nt = 0; nt < 2; ++nt)
#pragma unroll
        for (int r = 0; r < 4; ++r)
          Sred[ds][rg * 16 + l4 * 4 + r][(nt * 16 + l15) ^ wswz] = sp[rg][nt][r];
    lds_barrier();

    // --- reduce across waves + online softmax (1 row/thread, 2 cols/lane) ---
    {
      float sa = 0.0f, sb = 0.0f;
#pragma unroll
      for (int w2 = 0; w2 < 8; ++w2) {
        sa += Sred[w2][srow][l15 ^ rswz];
        sb += Sred[w2][srow][(l15 + 16) ^ rswz];
      }
      sa *= 0.03125f;  // 1/sqrt(1024)
      sb *= 0.03125f;
      if (s0 + l15 > t0 + srow) sa = -1e30f;        // causal mask
      if (s0 + l15 + 16 > t0 + srow) sb = -1e30f;
      float mt_ = fmaxf(sa, sb);
      mt_ = fmaxf(mt_, __shfl_xor(mt_, 1));
      mt_ = fmaxf(mt_, __shfl_xor(mt_, 2));
      mt_ = fmaxf(mt_, __shfl_xor(mt_, 4));
      mt_ = fmaxf(mt_, __shfl_xor(mt_, 8));
      const float mn = fmaxf(m_run, mt_);
      const float al = __expf(m_run - mn);
      m_run = mn;
      const float pa = __expf(sa - mn);
      const float pb = __expf(sb - mn);
      float ls = pa + pb;
      ls += __shfl_xor(ls, 1);
      ls += __shfl_xor(ls, 2);
      ls += __shfl_xor(ls, 4);
      ls += __shfl_xor(ls, 8);
      l_run = al * l_run + ls;
      P[srow][l15] = f2bf(pa);
      P[srow][l15 + 16] = f2bf(pb);
      Al[srow] = al;                 // 16-lane duplicate write, benign
    }
    lds_barrier();

    // --- rescale O (skipped when no row max moved) ---
    float av[2][4];
    int need = 0;
#pragma unroll
    for (int rg = 0; rg < 2; ++rg)
#pragma unroll
      for (int r = 0; r < 4; ++r) {
        av[rg][r] = Al[rg * 16 + l4 * 4 + r];
        need |= (av[rg][r] != 1.0f) ? 1 : 0;
      }
    if (__any(need)) {
#pragma unroll
      for (int rg = 0; rg < 2; ++rg)
#pragma unroll
        for (int nt = 0; nt < 8; ++nt)
#pragma unroll
          for (int r = 0; r < 4; ++r) acc[rg][nt][r] *= av[rg][r];
    }

    // --- PV: O += P[32,32] @ V[32, D-slice]  (full K=32 MFMA) ---
    bf16x8 pf[2];
#pragma unroll
    for (int rg = 0; rg < 2; ++rg)
      pf[rg] = *(const bf16x8*)&P[rg * 16 + l15][l4 * 8];
#pragma unroll
    for (int nt = 0; nt < 8; ++nt)
#pragma unroll
      for (int rg = 0; rg < 2; ++rg)
        acc[rg][nt] = __builtin_amdgcn_mfma_f32_16x16x32_bf16(pf[rg], vf[nt], acc[rg][nt], 0, 0, 0);

    // --- rotate K double buffer ---
#pragma unroll
    for (int q8 = 0; q8 < 8; ++q8) kcur[q8] = knxt[q8];
  }

  // --- epilogue: O / l, store bf16 ---
  __syncthreads();
  if (l15 == 0) Al[srow] = 1.0f / l_run;
  __syncthreads();
  float iv[2][4];
#pragma unroll
  for (int rg = 0; rg < 2; ++rg)
#pragma unroll
    for (int r = 0; r < 4; ++r) iv[rg][r] = Al[rg * 16 + l4 * 4 + r];
#pragma unroll
  for (int rg = 0; rg < 2; ++rg)
#pragma unroll
    for (int nt = 0; nt < 8; ++nt) {
      const size_t rbase = (base + t0 + rg * 16 + l4 * 4) * 1024 + ds * 128 + nt * 16 + l15;
#pragma unroll
      for (int r = 0; r < 4; ++r)
        ao[rbase + (size_t)r * 1024] = f2bf(acc[rg][nt][r] * iv[rg][r]);
    }
}

// ---------------------------------------------------------------------------
extern "C" void kernel_launch(void* const* d_in, const int* in_sizes, int n_in,
                              void* d_out, int out_size, void* d_ws, size_t ws_size,
                              hipStream_t stream) {
  const float* x     = (const float*)d_in[0];   // [4,4096,1024] fp32
  // d_in[1] = causal mask: ignored (computed analytically)
  const float* w_qkv = (const float*)d_in[2];   // [3072,1024] fp32
  const float* w_out = (const float*)d_in[3];   // [1024,1024] fp32
  float* out = (float*)d_out;                   // [4,4096,1024] fp32

  u16* ws  = (u16*)d_ws;
  u16* Qb  = ws;                    // 16384x1024 row-major
  u16* K4p = ws + 16777216;         // fragment-major K
  u16* Vb  = ws + 33554432;         // 16384x1024 row-major (V staging)
  u16* V4p = ws + 50331648;         // fragment-major V
  u16* aop = ws + 67108864;         // 16384x1024 attention output
  u16* xb  = aop;                   // bf16 x, aliases ao (dead before flash)
  u16* wqb = V4p;                   // bf16 w_qkv, aliases V4 front (dead before transpose)
  u16* wob = Vb;                    // bf16 w_out, aliases Vb front (dead after transpose)

  cvt_bf16<<<dim3(8192), 256, 0, stream>>>(x, xb, 2097152);      // 16384*1024/8
  cvt_bf16<<<dim3(1536), 256, 0, stream>>>(w_qkv, wqb, 393216);  // 3072*1024/8
  gemm_bt<u16, 1><<<dim3(24, 128), 256, 0, stream>>>(xb, wqb, Qb, 16384, 3072, 1024);
  transpose_v4<<<dim3(64, 16, 4), 256, 0, stream>>>(Vb, V4p);
  cvt_bf16<<<dim3(512), 256, 0, stream>>>(w_out, wob, 131072);   // 1024*1024/8
  flash_attn<<<dim3(512), 512, 0, stream>>>(Qb, K4p, V4p, aop);
  gemm_bt<float, 0><<<dim3(8, 128), 256, 0, stream>>>(aop, wob, out, 16384, 1024, 1024);
}